// Round 11
// baseline (253.488 us; speedup 1.0000x reference)
//
#include <hip/hip_runtime.h>
#include <math.h>

#define B_N    32768
#define D_N    128
#define HIST_N 30
#define M_N    15
#define H_N    4

#define TILE_ROWS   256
#define TILE_FLOATS (TILE_ROWS * HIST_N)          // 7680 floats = 30720 B
#define TILE_F4     (TILE_FLOATS / 4)             // 1920 float4
#define NBLOCKS     512                           // 2 resident blocks per CU
#define TPB         (B_N * D_N / TILE_ROWS / NBLOCKS)   // 32 contiguous tiles

// ---------------------------------------------------------------------------
// Fused persistent kernel, REGISTER-staged streaming (no global_load_lds).
// Rationale: r4/r5/r9/r10 (LDS-DMA staging) all cap at 3.6-4.3 TB/s across
// occupancy 8-16 waves/CU and pipeline depth 2-3 -> per-CU DMA throughput
// ceiling. Register load path is proven to 6.3 TB/s (m13). r2 tried this and
// spilled (VGPR=68, 519MB scratch) -> fixed here with __launch_bounds__(256,2).
// Pipeline: load rB <- T_{k+1} (8x dwordx4); [compiler emits counted vmcnt
// for rA only]; ds_write rA -> buf; lgkmcnt(0); raw s_barrier (NO vmcnt
// drain -> rB stays in flight); compute buf; store; swap. One barrier/iter.
// ---------------------------------------------------------------------------
__global__ __launch_bounds__(256, 2) void fused_kernel(
        const float* __restrict__ pa,
        const float* __restrict__ w1,
        const float* __restrict__ b1,
        const float* __restrict__ b2,
        const float* __restrict__ b3,
        const float* __restrict__ cw,
        const float* __restrict__ ss,
        const float* __restrict__ sh,
        const float* __restrict__ al,
        const float* __restrict__ rs,
        float* __restrict__ out) {
    const int tid   = threadIdx.x;
    const int lane  = tid & 63;
    const int wv_id = tid >> 6;                 // wave 0..3
    const int d     = tid & 127;

    __shared__ __align__(16) float4 lds4[2][TILE_F4];     // 2 x 30720 B
    __shared__ float W1c[H_N][D_N];                       // 2 KB
    __shared__ float Gsh[16];
    __shared__ float Msh[32];                             // M2[16], M3[16]

    const float4* pa4 = (const float4*)pa;
    const size_t tile0 = (size_t)blockIdx.x * TPB;        // contiguous chunk

    // dense register staging: 7 full rounds + tail (128 f4) split as
    // lane<32 of each wave -> every wave issues exactly 8 uniform loads.
    auto load_tile = [&](size_t t, float4* r) {
        const float4* src = pa4 + t * TILE_F4;
#pragma unroll
        for (int j = 0; j < 7; ++j) r[j] = src[j * 256 + tid];
        if (lane < 32) r[7] = src[1792 + wv_id * 32 + lane];
    };
    auto write_tile = [&](int buf, const float4* r) {
        float4* L4 = &lds4[buf][0];
#pragma unroll
        for (int j = 0; j < 7; ++j) L4[j * 256 + tid] = r[j];
        if (lane < 32) L4[1792 + wv_id * 32 + lane] = r[7];
    };

    float4 rA[8], rB[8];
    load_tile(tile0, rA);     // T0 in flight

    // ---- per-d parameter loads (overlap T0's loads) ----
    float wv[M_N][H_N];
#pragma unroll
    for (int m = 0; m < M_N; ++m)
#pragma unroll
        for (int h = 0; h < H_N; ++h)
            wv[m][h] = w1[(m * H_N + h) * D_N + d];

    float b1v[H_N], b2v[H_N];
#pragma unroll
    for (int h = 0; h < H_N; ++h) {
        b1v[h] = b1[h * D_N + d];
        b2v[h] = b2[h * D_N + d];
    }
    const float b3v = b3[d];

    // ---- softmax(cw), redundant per-thread ----
    float swm[M_N];
    {
        float mx = cw[0];
#pragma unroll
        for (int m = 1; m < M_N; ++m) mx = fmaxf(mx, cw[m]);
        float s = 0.f;
#pragma unroll
        for (int m = 0; m < M_N; ++m) { swm[m] = expf(cw[m] - mx); s += swm[m]; }
        float inv = 1.f / s;
#pragma unroll
        for (int m = 0; m < M_N; ++m) swm[m] *= inv;
    }

    // ---- W1c into LDS ----
    if (tid < 128) {
#pragma unroll
        for (int h = 0; h < H_N; ++h) {
            float acc = 0.f;
#pragma unroll
            for (int m = 0; m < M_N; ++m)
                acc = fmaf(swm[m], w1[(m * H_N + h) * D_N + tid], acc);
            W1c[h][tid] = acc;
        }
    }
    asm volatile("s_waitcnt lgkmcnt(0)" ::: "memory");
    __builtin_amdgcn_s_barrier();

    // ---- Gram (16 threads, staggered) ----
    if (tid < 16) {
        const int i = tid >> 2, j = tid & 3;
        float s = 0.f;
        for (int st = 0; st < 128; ++st) {
            int dd = (st + tid * 8) & 127;
            s = fmaf(W1c[i][dd], W1c[j][dd], s);
        }
        Gsh[tid] = s;
    }
    asm volatile("s_waitcnt lgkmcnt(0)" ::: "memory");
    __builtin_amdgcn_s_barrier();

    // ---- thread 0: Jacobi + two-stage spectral scalars -> M2, M3 ----
    if (tid == 0) {
        float G[4][4], U[4][4];
#pragma unroll
        for (int i = 0; i < 4; ++i)
#pragma unroll
            for (int j = 0; j < 4; ++j) {
                G[i][j] = Gsh[i * 4 + j];
                U[i][j] = (i == j) ? 1.f : 0.f;
            }
        for (int sweep = 0; sweep < 6; ++sweep)
            for (int p = 0; p < 3; ++p)
                for (int q = p + 1; q < 4; ++q) {
                    float apq = G[p][q];
                    if (fabsf(apq) < 1e-30f) continue;
                    float theta = (G[q][q] - G[p][p]) / (2.f * apq);
                    float t = ((theta >= 0.f) ? 1.f : -1.f) /
                              (fabsf(theta) + sqrtf(theta * theta + 1.f));
                    float c = 1.f / sqrtf(t * t + 1.f), sn = t * c;
                    for (int i = 0; i < 4; ++i) {
                        float gip = G[i][p], giq = G[i][q];
                        G[i][p] = c * gip - sn * giq;
                        G[i][q] = sn * gip + c * giq;
                    }
                    for (int i = 0; i < 4; ++i) {
                        float gpi = G[p][i], gqi = G[q][i];
                        G[p][i] = c * gpi - sn * gqi;
                        G[q][i] = sn * gpi + c * gqi;
                    }
                    for (int i = 0; i < 4; ++i) {
                        float uip = U[i][p], uiq = U[i][q];
                        U[i][p] = c * uip - sn * uiq;
                        U[i][q] = sn * uip + c * uiq;
                    }
                }
        float lam[4];
#pragma unroll
        for (int i = 0; i < 4; ++i) lam[i] = G[i][i];
        int ord[4] = {0, 1, 2, 3};
        for (int i = 0; i < 4; ++i)
            for (int j = i + 1; j < 4; ++j)
                if (lam[ord[j]] > lam[ord[i]]) { int t2 = ord[i]; ord[i] = ord[j]; ord[j] = t2; }

        const float a = al[0], r = rs[0];
        float c1[4], S2a[4];
        for (int p = 0; p < 4; ++p) {
            int e = ord[p];
            float S = sqrtf(fmaxf(lam[e], 0.f));
            float x = ss[p];
            float sp = (x > 20.f) ? x : log1pf(expf(x));
            float ratio = (S > 1e-30f) ? ((sp * S + sh[p]) / S) : sp;
            c1[e] = a * ratio + r;
            S2a[e] = fabsf(c1[e]) * S;      // |singular values| of W2
        }
        int ord2[4] = {0, 1, 2, 3};
        for (int i = 0; i < 4; ++i)
            for (int j = i + 1; j < 4; ++j)
                if (S2a[ord2[j]] > S2a[ord2[i]]) { int t2 = ord2[i]; ord2[i] = ord2[j]; ord2[j] = t2; }
        float c12[4];
        for (int p = 0; p < 4; ++p) {
            int e = ord2[p];
            float Sa = S2a[e];
            float x = ss[p];
            float sp = (x > 20.f) ? x : log1pf(expf(x));
            float ratio2 = (Sa > 1e-30f) ? ((sp * Sa + sh[p]) / Sa) : sp;
            c12[e] = (a * ratio2 + r) * c1[e];
        }
#pragma unroll
        for (int i = 0; i < 4; ++i)
#pragma unroll
            for (int j = 0; j < 4; ++j) {
                float m2 = 0.f, m3 = 0.f;
#pragma unroll
                for (int e = 0; e < 4; ++e) {
                    float uu = U[i][e] * U[j][e];
                    m2 = fmaf(uu, c1[e], m2);
                    m3 = fmaf(uu, c12[e], m3);
                }
                Msh[i * 4 + j] = m2;
                Msh[16 + i * 4 + j] = m3;
            }
    }
    asm volatile("s_waitcnt lgkmcnt(0)" ::: "memory");
    __builtin_amdgcn_s_barrier();

    // ---- per-thread W2/W3 columns ----
    float w2v[H_N], w3v[H_N];
#pragma unroll
    for (int h = 0; h < H_N; ++h) {
        float s2 = 0.f, s3 = 0.f;
#pragma unroll
        for (int k4 = 0; k4 < 4; ++k4) {
            float wc = W1c[k4][d];
            s2 = fmaf(Msh[h * 4 + k4], wc, s2);
            s3 = fmaf(Msh[16 + h * 4 + k4], wc, s3);
        }
        w2v[h] = s2;
        w3v[h] = s3;
    }

    // per-thread compute of one row from the staged tile
    auto compute_tile = [&](int buf, size_t t) {
        const float* L = (const float*)&lds4[buf][0] + tid * HIST_N + (HIST_N - M_N);
        float x0 = L[0];
        float h1[H_N];
#pragma unroll
        for (int h = 0; h < H_N; ++h) h1[h] = x0 * wv[0][h];
#pragma unroll
        for (int c = 0; c < 7; ++c) {
            float2 q = *(const float2*)(L + 1 + 2 * c);   // 8B-aligned
#pragma unroll
            for (int h = 0; h < H_N; ++h) h1[h] = fmaf(q.x, wv[1 + 2 * c][h], h1[h]);
#pragma unroll
            for (int h = 0; h < H_N; ++h) h1[h] = fmaf(q.y, wv[2 + 2 * c][h], h1[h]);
        }
        float acc = b3v;
#pragma unroll
        for (int h = 0; h < H_N; ++h) {
            float v = fmaxf(h1[h] + b1v[h], 0.f);
            float u = fmaxf(fmaf(v, w2v[h], b2v[h]), 0.f);
            acc = fmaf(u, w3v[h], acc);
        }
        out[t * TILE_ROWS + tid] = acc;
    };

    // ---- main loop, 2x unrolled for static rA/rB (TPB even) ----
    for (int k = 0; k < TPB; k += 2) {
        // iter k: rA holds T_k (in flight)
        if (k + 1 < TPB) load_tile(tile0 + k + 1, rB);
        write_tile(k & 1 ? 1 : 0, rA);          // compiler emits counted vmcnt for rA
        asm volatile("s_waitcnt lgkmcnt(0)" ::: "memory");
        __builtin_amdgcn_s_barrier();           // raw barrier: rB loads stay in flight
        asm volatile("" ::: "memory");
        compute_tile(0, tile0 + k);
        asm volatile("" ::: "memory");

        // iter k+1: rB holds T_{k+1}
        if (k + 2 < TPB) load_tile(tile0 + k + 2, rA);
        write_tile(1, rB);
        asm volatile("s_waitcnt lgkmcnt(0)" ::: "memory");
        __builtin_amdgcn_s_barrier();
        asm volatile("" ::: "memory");
        compute_tile(1, tile0 + k + 1);
        asm volatile("" ::: "memory");
    }
}

extern "C" void kernel_launch(void* const* d_in, const int* in_sizes, int n_in,
                              void* d_out, int out_size, void* d_ws, size_t ws_size,
                              hipStream_t stream) {
    const float* pa = (const float*)d_in[0];   // (B, D, HIST)
    const float* w1 = (const float*)d_in[1];   // (M, H, D)
    const float* b1 = (const float*)d_in[2];   // (1, H, D)
    const float* b2 = (const float*)d_in[3];   // (1, H, D)
    const float* b3 = (const float*)d_in[4];   // (1, D)
    const float* cw = (const float*)d_in[5];   // (M,)
    const float* ss = (const float*)d_in[6];   // (RANK,)
    const float* sh = (const float*)d_in[7];   // (RANK,)
    const float* al = (const float*)d_in[8];   // (1,)
    const float* rs = (const float*)d_in[9];   // (1,)
    float* out = (float*)d_out;                // (B, D) f32

    fused_kernel<<<NBLOCKS, 256, 0, stream>>>(pa, w1, b1, b2, b3, cw, ss, sh, al, rs, out);
}

// Round 12
// 123.071 us; speedup vs baseline: 2.0597x; 2.0597x over previous
//
#include <hip/hip_runtime.h>
#include <math.h>

#define B_N    32768
#define D_N    128
#define HIST_N 30
#define M_N    15
#define H_N    4

#define TILE_ROWS   256
#define TILE_FLOATS (TILE_ROWS * HIST_N)          // 7680 floats = 30720 B
#define TILE_F4     (TILE_FLOATS / 4)             // 1920 float4
#define WAVE_F4     480                           // per-wave: 64 rows = 480 f4
#define NBLOCKS     512                           // 2 resident blocks per CU
#define TPB         (B_N * D_N / TILE_ROWS / NBLOCKS)   // 32 contiguous tiles

// ---------------------------------------------------------------------------
// Fused persistent kernel, register-staged, WAVE-PRIVATE pipeline.
// r11 (reg-staged + block barrier + reg arrays) hit 253us; suspects were
// scratch-spilled arrays and/or barrier coupling. This round: named registers
// a0..a7/b0..b7 (SROA-proof), each wave stages & computes its own 64 rows
// (intra-wave LDS ordering -> NO main-loop barriers), counted vmcnt keeps the
// next tile's 8 loads in flight across the whole compute phase.
//   iter k (even->set A/buf0, odd->set B/buf1):
//     vmcnt(k==0?8 : k==last?0 : 9)   // drain tile k's loads only
//     ds_write set -> buf ; lgkmcnt(0)
//     compute 64 rows from buf ; store out
//     issue loads T_{k+2} into the just-freed set
// ---------------------------------------------------------------------------
__global__ __launch_bounds__(256, 2) void fused_kernel(
        const float* __restrict__ pa,
        const float* __restrict__ w1,
        const float* __restrict__ b1,
        const float* __restrict__ b2,
        const float* __restrict__ b3,
        const float* __restrict__ cw,
        const float* __restrict__ ss,
        const float* __restrict__ sh,
        const float* __restrict__ al,
        const float* __restrict__ rs,
        float* __restrict__ out) {
    const int tid   = threadIdx.x;
    const int lane  = tid & 63;
    const int wv_id = tid >> 6;                 // wave 0..3
    const int d     = tid & 127;

    __shared__ __align__(16) float4 lds4[2][TILE_F4];     // 2 x 30720 B
    __shared__ float W1c[H_N][D_N];                       // 2 KB
    __shared__ float Gsh[16];
    __shared__ float Msh[32];                             // M2[16], M3[16]

    const float4* pa4 = (const float4*)pa;
    const size_t tile0 = (size_t)blockIdx.x * TPB;        // contiguous chunk

#define LOAD_SET(v0,v1,v2,v3,v4,v5,v6,v7,t) do {                       \
        const float4* s_ = pa4 + (size_t)(t) * TILE_F4 + wv_id * WAVE_F4; \
        v0 = s_[lane];        v1 = s_[64 + lane];                      \
        v2 = s_[128 + lane];  v3 = s_[192 + lane];                     \
        v4 = s_[256 + lane];  v5 = s_[320 + lane];                     \
        v6 = s_[384 + lane];                                           \
        if (lane < 32) v7 = s_[448 + lane];                            \
    } while (0)

#define WRITE_SET(v0,v1,v2,v3,v4,v5,v6,v7,buf) do {                    \
        float4* L_ = &lds4[buf][0] + wv_id * WAVE_F4;                  \
        L_[lane] = v0;        L_[64 + lane] = v1;                      \
        L_[128 + lane] = v2;  L_[192 + lane] = v3;                     \
        L_[256 + lane] = v4;  L_[320 + lane] = v5;                     \
        L_[384 + lane] = v6;                                           \
        if (lane < 32) L_[448 + lane] = v7;                            \
    } while (0)

    float4 a0, a1, a2, a3, a4, a5, a6, a7;
    float4 b0, b1r, b2r, b3r, b4, b5, b6, b7;
    a7 = make_float4(0.f, 0.f, 0.f, 0.f);
    b7 = make_float4(0.f, 0.f, 0.f, 0.f);

    // prologue: tiles 0 and 1 in flight before anything else
    LOAD_SET(a0, a1, a2, a3, a4, a5, a6, a7, tile0);
    LOAD_SET(b0, b1r, b2r, b3r, b4, b5, b6, b7, tile0 + 1);

    // ---- per-d parameter loads (overlap the prologue loads) ----
    float wv[M_N][H_N];
#pragma unroll
    for (int m = 0; m < M_N; ++m)
#pragma unroll
        for (int h = 0; h < H_N; ++h)
            wv[m][h] = w1[(m * H_N + h) * D_N + d];

    float b1v[H_N], b2v[H_N];
#pragma unroll
    for (int h = 0; h < H_N; ++h) {
        b1v[h] = b1[h * D_N + d];
        b2v[h] = b2[h * D_N + d];
    }
    const float b3v = b3[d];

    // ---- softmax(cw), redundant per-thread ----
    float swm[M_N];
    {
        float mx = cw[0];
#pragma unroll
        for (int m = 1; m < M_N; ++m) mx = fmaxf(mx, cw[m]);
        float s = 0.f;
#pragma unroll
        for (int m = 0; m < M_N; ++m) { swm[m] = expf(cw[m] - mx); s += swm[m]; }
        float inv = 1.f / s;
#pragma unroll
        for (int m = 0; m < M_N; ++m) swm[m] *= inv;
    }

    // ---- W1c into LDS ----
    if (tid < 128) {
#pragma unroll
        for (int h = 0; h < H_N; ++h) {
            float acc = 0.f;
#pragma unroll
            for (int m = 0; m < M_N; ++m)
                acc = fmaf(swm[m], w1[(m * H_N + h) * D_N + tid], acc);
            W1c[h][tid] = acc;
        }
    }
    asm volatile("s_waitcnt lgkmcnt(0)" ::: "memory");
    __builtin_amdgcn_s_barrier();

    // ---- Gram (16 threads, staggered) ----
    if (tid < 16) {
        const int i = tid >> 2, j = tid & 3;
        float s = 0.f;
        for (int st = 0; st < 128; ++st) {
            int dd = (st + tid * 8) & 127;
            s = fmaf(W1c[i][dd], W1c[j][dd], s);
        }
        Gsh[tid] = s;
    }
    asm volatile("s_waitcnt lgkmcnt(0)" ::: "memory");
    __builtin_amdgcn_s_barrier();

    // ---- thread 0: Jacobi + two-stage spectral scalars -> M2, M3 ----
    if (tid == 0) {
        float G[4][4], U[4][4];
#pragma unroll
        for (int i = 0; i < 4; ++i)
#pragma unroll
            for (int j = 0; j < 4; ++j) {
                G[i][j] = Gsh[i * 4 + j];
                U[i][j] = (i == j) ? 1.f : 0.f;
            }
        for (int sweep = 0; sweep < 6; ++sweep)
            for (int p = 0; p < 3; ++p)
                for (int q = p + 1; q < 4; ++q) {
                    float apq = G[p][q];
                    if (fabsf(apq) < 1e-30f) continue;
                    float theta = (G[q][q] - G[p][p]) / (2.f * apq);
                    float t = ((theta >= 0.f) ? 1.f : -1.f) /
                              (fabsf(theta) + sqrtf(theta * theta + 1.f));
                    float c = 1.f / sqrtf(t * t + 1.f), sn = t * c;
                    for (int i = 0; i < 4; ++i) {
                        float gip = G[i][p], giq = G[i][q];
                        G[i][p] = c * gip - sn * giq;
                        G[i][q] = sn * gip + c * giq;
                    }
                    for (int i = 0; i < 4; ++i) {
                        float gpi = G[p][i], gqi = G[q][i];
                        G[p][i] = c * gpi - sn * gqi;
                        G[q][i] = sn * gpi + c * gqi;
                    }
                    for (int i = 0; i < 4; ++i) {
                        float uip = U[i][p], uiq = U[i][q];
                        U[i][p] = c * uip - sn * uiq;
                        U[i][q] = sn * uip + c * uiq;
                    }
                }
        float lam[4];
#pragma unroll
        for (int i = 0; i < 4; ++i) lam[i] = G[i][i];
        int ord[4] = {0, 1, 2, 3};
        for (int i = 0; i < 4; ++i)
            for (int j = i + 1; j < 4; ++j)
                if (lam[ord[j]] > lam[ord[i]]) { int t2 = ord[i]; ord[i] = ord[j]; ord[j] = t2; }

        const float a = al[0], r = rs[0];
        float c1[4], S2a[4];
        for (int p = 0; p < 4; ++p) {
            int e = ord[p];
            float S = sqrtf(fmaxf(lam[e], 0.f));
            float x = ss[p];
            float sp = (x > 20.f) ? x : log1pf(expf(x));
            float ratio = (S > 1e-30f) ? ((sp * S + sh[p]) / S) : sp;
            c1[e] = a * ratio + r;
            S2a[e] = fabsf(c1[e]) * S;      // |singular values| of W2
        }
        int ord2[4] = {0, 1, 2, 3};
        for (int i = 0; i < 4; ++i)
            for (int j = i + 1; j < 4; ++j)
                if (S2a[ord2[j]] > S2a[ord2[i]]) { int t2 = ord2[i]; ord2[i] = ord2[j]; ord2[j] = t2; }
        float c12[4];
        for (int p = 0; p < 4; ++p) {
            int e = ord2[p];
            float Sa = S2a[e];
            float x = ss[p];
            float sp = (x > 20.f) ? x : log1pf(expf(x));
            float ratio2 = (Sa > 1e-30f) ? ((sp * Sa + sh[p]) / Sa) : sp;
            c12[e] = (a * ratio2 + r) * c1[e];
        }
#pragma unroll
        for (int i = 0; i < 4; ++i)
#pragma unroll
            for (int j = 0; j < 4; ++j) {
                float m2 = 0.f, m3 = 0.f;
#pragma unroll
                for (int e = 0; e < 4; ++e) {
                    float uu = U[i][e] * U[j][e];
                    m2 = fmaf(uu, c1[e], m2);
                    m3 = fmaf(uu, c12[e], m3);
                }
                Msh[i * 4 + j] = m2;
                Msh[16 + i * 4 + j] = m3;
            }
    }
    asm volatile("s_waitcnt lgkmcnt(0)" ::: "memory");
    __builtin_amdgcn_s_barrier();

    // ---- per-thread W2/W3 columns ----
    float w2v[H_N], w3v[H_N];
#pragma unroll
    for (int h = 0; h < H_N; ++h) {
        float s2 = 0.f, s3 = 0.f;
#pragma unroll
        for (int k4 = 0; k4 < 4; ++k4) {
            float wc = W1c[k4][d];
            s2 = fmaf(Msh[h * 4 + k4], wc, s2);
            s3 = fmaf(Msh[16 + h * 4 + k4], wc, s3);
        }
        w2v[h] = s2;
        w3v[h] = s3;
    }

    // thread computes row = lane of its wave's 64 rows
    const int rd_base = wv_id * (WAVE_F4 * 4) + lane * HIST_N + (HIST_N - M_N);

    auto compute_tile = [&](int buf, size_t t) {
        const float* L = (const float*)&lds4[buf][0] + rd_base;
        float x0 = L[0];
        float h1[H_N];
#pragma unroll
        for (int h = 0; h < H_N; ++h) h1[h] = x0 * wv[0][h];
#pragma unroll
        for (int c = 0; c < 7; ++c) {
            float2 q = *(const float2*)(L + 1 + 2 * c);   // 8B-aligned
#pragma unroll
            for (int h = 0; h < H_N; ++h) h1[h] = fmaf(q.x, wv[1 + 2 * c][h], h1[h]);
#pragma unroll
            for (int h = 0; h < H_N; ++h) h1[h] = fmaf(q.y, wv[2 + 2 * c][h], h1[h]);
        }
        float acc = b3v;
#pragma unroll
        for (int h = 0; h < H_N; ++h) {
            float v = fmaxf(h1[h] + b1v[h], 0.f);
            float u = fmaxf(fmaf(v, w2v[h], b2v[h]), 0.f);
            acc = fmaf(u, w3v[h], acc);
        }
        out[t * TILE_ROWS + wv_id * 64 + lane] = acc;
    };

    // ---- main loop: wave-private, no barriers, counted vmcnt ----
    for (int k = 0; k < TPB; k += 2) {
        // tile k: set A -> buf0
        if (k == 0) asm volatile("s_waitcnt vmcnt(8)" ::: "memory");
        else        asm volatile("s_waitcnt vmcnt(9)" ::: "memory");
        WRITE_SET(a0, a1, a2, a3, a4, a5, a6, a7, 0);
        asm volatile("s_waitcnt lgkmcnt(0)" ::: "memory");
        compute_tile(0, tile0 + k);
        if (k + 2 < TPB) LOAD_SET(a0, a1, a2, a3, a4, a5, a6, a7, tile0 + k + 2);

        // tile k+1: set B -> buf1
        if (k + 1 == TPB - 1) asm volatile("s_waitcnt vmcnt(0)" ::: "memory");
        else                  asm volatile("s_waitcnt vmcnt(9)" ::: "memory");
        WRITE_SET(b0, b1r, b2r, b3r, b4, b5, b6, b7, 1);
        asm volatile("s_waitcnt lgkmcnt(0)" ::: "memory");
        compute_tile(1, tile0 + k + 1);
        if (k + 3 < TPB) LOAD_SET(b0, b1r, b2r, b3r, b4, b5, b6, b7, tile0 + k + 3);
    }
#undef LOAD_SET
#undef WRITE_SET
}

extern "C" void kernel_launch(void* const* d_in, const int* in_sizes, int n_in,
                              void* d_out, int out_size, void* d_ws, size_t ws_size,
                              hipStream_t stream) {
    const float* pa = (const float*)d_in[0];   // (B, D, HIST)
    const float* w1 = (const float*)d_in[1];   // (M, H, D)
    const float* b1 = (const float*)d_in[2];   // (1, H, D)
    const float* b2 = (const float*)d_in[3];   // (1, H, D)
    const float* b3 = (const float*)d_in[4];   // (1, D)
    const float* cw = (const float*)d_in[5];   // (M,)
    const float* ss = (const float*)d_in[6];   // (RANK,)
    const float* sh = (const float*)d_in[7];   // (RANK,)
    const float* al = (const float*)d_in[8];   // (1,)
    const float* rs = (const float*)d_in[9];   // (1,)
    float* out = (float*)d_out;                // (B, D) f32

    fused_kernel<<<NBLOCKS, 256, 0, stream>>>(pa, w1, b1, b2, b3, cw, ss, sh, al, rs, out);
}

// Round 13
// 119.395 us; speedup vs baseline: 2.1231x; 1.0308x over previous
//
#include <hip/hip_runtime.h>
#include <math.h>

#define B_N    32768
#define D_N    128
#define HIST_N 30
#define M_N    15
#define H_N    4

#define TILE_ROWS   256
#define TILE_FLOATS (TILE_ROWS * HIST_N)          // 7680 floats = 30720 B
#define TILE_F4     (TILE_FLOATS / 4)             // 1920 float4
#define WAVE_F4     480                           // per-wave: 64 rows = 480 f4
#define NBLOCKS     256                           // 1 block/CU: ONE 1.92MB stream per CU
#define TPB         (B_N * D_N / TILE_ROWS / NBLOCKS)   // 64 contiguous tiles

// ---------------------------------------------------------------------------
// Fused persistent kernel, register-staged, WAVE-PRIVATE pipeline (r12 body).
// r13 single-variable change: NBLOCKS 512 -> 256 (same 8 waves/CU occupancy,
// half the concurrent HBM read streams, 2x the per-stream contiguity).
// Probe: r5(DMA)=121.7, r12(reg)=123.1 converged at ~4.3TB/s despite 72KB/CU
// outstanding (~11x latency-BW product) -> bandwidth-queue-bound, not
// latency-bound. Only DRAM stream locality remains untested.
//   iter k (even->set A/buf0, odd->set B/buf1):
//     vmcnt(k==0?8 : k==last?0 : 9)   // drain tile k's loads only
//     ds_write set -> buf ; lgkmcnt(0)
//     compute 64 rows from buf ; store out
//     issue loads T_{k+2} into the just-freed set
// ---------------------------------------------------------------------------
__global__ __launch_bounds__(256, 2) void fused_kernel(
        const float* __restrict__ pa,
        const float* __restrict__ w1,
        const float* __restrict__ b1,
        const float* __restrict__ b2,
        const float* __restrict__ b3,
        const float* __restrict__ cw,
        const float* __restrict__ ss,
        const float* __restrict__ sh,
        const float* __restrict__ al,
        const float* __restrict__ rs,
        float* __restrict__ out) {
    const int tid   = threadIdx.x;
    const int lane  = tid & 63;
    const int wv_id = tid >> 6;                 // wave 0..3
    const int d     = tid & 127;

    __shared__ __align__(16) float4 lds4[2][TILE_F4];     // 2 x 30720 B
    __shared__ float W1c[H_N][D_N];                       // 2 KB
    __shared__ float Gsh[16];
    __shared__ float Msh[32];                             // M2[16], M3[16]

    const float4* pa4 = (const float4*)pa;
    const size_t tile0 = (size_t)blockIdx.x * TPB;        // contiguous chunk

#define LOAD_SET(v0,v1,v2,v3,v4,v5,v6,v7,t) do {                       \
        const float4* s_ = pa4 + (size_t)(t) * TILE_F4 + wv_id * WAVE_F4; \
        v0 = s_[lane];        v1 = s_[64 + lane];                      \
        v2 = s_[128 + lane];  v3 = s_[192 + lane];                     \
        v4 = s_[256 + lane];  v5 = s_[320 + lane];                     \
        v6 = s_[384 + lane];                                           \
        if (lane < 32) v7 = s_[448 + lane];                            \
    } while (0)

#define WRITE_SET(v0,v1,v2,v3,v4,v5,v6,v7,buf) do {                    \
        float4* L_ = &lds4[buf][0] + wv_id * WAVE_F4;                  \
        L_[lane] = v0;        L_[64 + lane] = v1;                      \
        L_[128 + lane] = v2;  L_[192 + lane] = v3;                     \
        L_[256 + lane] = v4;  L_[320 + lane] = v5;                     \
        L_[384 + lane] = v6;                                           \
        if (lane < 32) L_[448 + lane] = v7;                            \
    } while (0)

    float4 a0, a1, a2, a3, a4, a5, a6, a7;
    float4 b0, b1r, b2r, b3r, b4, b5, b6, b7;
    a7 = make_float4(0.f, 0.f, 0.f, 0.f);
    b7 = make_float4(0.f, 0.f, 0.f, 0.f);

    // prologue: tiles 0 and 1 in flight before anything else
    LOAD_SET(a0, a1, a2, a3, a4, a5, a6, a7, tile0);
    LOAD_SET(b0, b1r, b2r, b3r, b4, b5, b6, b7, tile0 + 1);

    // ---- per-d parameter loads (overlap the prologue loads) ----
    float wv[M_N][H_N];
#pragma unroll
    for (int m = 0; m < M_N; ++m)
#pragma unroll
        for (int h = 0; h < H_N; ++h)
            wv[m][h] = w1[(m * H_N + h) * D_N + d];

    float b1v[H_N], b2v[H_N];
#pragma unroll
    for (int h = 0; h < H_N; ++h) {
        b1v[h] = b1[h * D_N + d];
        b2v[h] = b2[h * D_N + d];
    }
    const float b3v = b3[d];

    // ---- softmax(cw), redundant per-thread ----
    float swm[M_N];
    {
        float mx = cw[0];
#pragma unroll
        for (int m = 1; m < M_N; ++m) mx = fmaxf(mx, cw[m]);
        float s = 0.f;
#pragma unroll
        for (int m = 0; m < M_N; ++m) { swm[m] = expf(cw[m] - mx); s += swm[m]; }
        float inv = 1.f / s;
#pragma unroll
        for (int m = 0; m < M_N; ++m) swm[m] *= inv;
    }

    // ---- W1c into LDS ----
    if (tid < 128) {
#pragma unroll
        for (int h = 0; h < H_N; ++h) {
            float acc = 0.f;
#pragma unroll
            for (int m = 0; m < M_N; ++m)
                acc = fmaf(swm[m], w1[(m * H_N + h) * D_N + tid], acc);
            W1c[h][tid] = acc;
        }
    }
    asm volatile("s_waitcnt lgkmcnt(0)" ::: "memory");
    __builtin_amdgcn_s_barrier();

    // ---- Gram (16 threads, staggered) ----
    if (tid < 16) {
        const int i = tid >> 2, j = tid & 3;
        float s = 0.f;
        for (int st = 0; st < 128; ++st) {
            int dd = (st + tid * 8) & 127;
            s = fmaf(W1c[i][dd], W1c[j][dd], s);
        }
        Gsh[tid] = s;
    }
    asm volatile("s_waitcnt lgkmcnt(0)" ::: "memory");
    __builtin_amdgcn_s_barrier();

    // ---- thread 0: Jacobi + two-stage spectral scalars -> M2, M3 ----
    if (tid == 0) {
        float G[4][4], U[4][4];
#pragma unroll
        for (int i = 0; i < 4; ++i)
#pragma unroll
            for (int j = 0; j < 4; ++j) {
                G[i][j] = Gsh[i * 4 + j];
                U[i][j] = (i == j) ? 1.f : 0.f;
            }
        for (int sweep = 0; sweep < 6; ++sweep)
            for (int p = 0; p < 3; ++p)
                for (int q = p + 1; q < 4; ++q) {
                    float apq = G[p][q];
                    if (fabsf(apq) < 1e-30f) continue;
                    float theta = (G[q][q] - G[p][p]) / (2.f * apq);
                    float t = ((theta >= 0.f) ? 1.f : -1.f) /
                              (fabsf(theta) + sqrtf(theta * theta + 1.f));
                    float c = 1.f / sqrtf(t * t + 1.f), sn = t * c;
                    for (int i = 0; i < 4; ++i) {
                        float gip = G[i][p], giq = G[i][q];
                        G[i][p] = c * gip - sn * giq;
                        G[i][q] = sn * gip + c * giq;
                    }
                    for (int i = 0; i < 4; ++i) {
                        float gpi = G[p][i], gqi = G[q][i];
                        G[p][i] = c * gpi - sn * gqi;
                        G[q][i] = sn * gpi + c * gqi;
                    }
                    for (int i = 0; i < 4; ++i) {
                        float uip = U[i][p], uiq = U[i][q];
                        U[i][p] = c * uip - sn * uiq;
                        U[i][q] = sn * uip + c * uiq;
                    }
                }
        float lam[4];
#pragma unroll
        for (int i = 0; i < 4; ++i) lam[i] = G[i][i];
        int ord[4] = {0, 1, 2, 3};
        for (int i = 0; i < 4; ++i)
            for (int j = i + 1; j < 4; ++j)
                if (lam[ord[j]] > lam[ord[i]]) { int t2 = ord[i]; ord[i] = ord[j]; ord[j] = t2; }

        const float a = al[0], r = rs[0];
        float c1[4], S2a[4];
        for (int p = 0; p < 4; ++p) {
            int e = ord[p];
            float S = sqrtf(fmaxf(lam[e], 0.f));
            float x = ss[p];
            float sp = (x > 20.f) ? x : log1pf(expf(x));
            float ratio = (S > 1e-30f) ? ((sp * S + sh[p]) / S) : sp;
            c1[e] = a * ratio + r;
            S2a[e] = fabsf(c1[e]) * S;      // |singular values| of W2
        }
        int ord2[4] = {0, 1, 2, 3};
        for (int i = 0; i < 4; ++i)
            for (int j = i + 1; j < 4; ++j)
                if (S2a[ord2[j]] > S2a[ord2[i]]) { int t2 = ord2[i]; ord2[i] = ord2[j]; ord2[j] = t2; }
        float c12[4];
        for (int p = 0; p < 4; ++p) {
            int e = ord2[p];
            float Sa = S2a[e];
            float x = ss[p];
            float sp = (x > 20.f) ? x : log1pf(expf(x));
            float ratio2 = (Sa > 1e-30f) ? ((sp * Sa + sh[p]) / Sa) : sp;
            c12[e] = (a * ratio2 + r) * c1[e];
        }
#pragma unroll
        for (int i = 0; i < 4; ++i)
#pragma unroll
            for (int j = 0; j < 4; ++j) {
                float m2 = 0.f, m3 = 0.f;
#pragma unroll
                for (int e = 0; e < 4; ++e) {
                    float uu = U[i][e] * U[j][e];
                    m2 = fmaf(uu, c1[e], m2);
                    m3 = fmaf(uu, c12[e], m3);
                }
                Msh[i * 4 + j] = m2;
                Msh[16 + i * 4 + j] = m3;
            }
    }
    asm volatile("s_waitcnt lgkmcnt(0)" ::: "memory");
    __builtin_amdgcn_s_barrier();

    // ---- per-thread W2/W3 columns ----
    float w2v[H_N], w3v[H_N];
#pragma unroll
    for (int h = 0; h < H_N; ++h) {
        float s2 = 0.f, s3 = 0.f;
#pragma unroll
        for (int k4 = 0; k4 < 4; ++k4) {
            float wc = W1c[k4][d];
            s2 = fmaf(Msh[h * 4 + k4], wc, s2);
            s3 = fmaf(Msh[16 + h * 4 + k4], wc, s3);
        }
        w2v[h] = s2;
        w3v[h] = s3;
    }

    // thread computes row = lane of its wave's 64 rows
    const int rd_base = wv_id * (WAVE_F4 * 4) + lane * HIST_N + (HIST_N - M_N);

    auto compute_tile = [&](int buf, size_t t) {
        const float* L = (const float*)&lds4[buf][0] + rd_base;
        float x0 = L[0];
        float h1[H_N];
#pragma unroll
        for (int h = 0; h < H_N; ++h) h1[h] = x0 * wv[0][h];
#pragma unroll
        for (int c = 0; c < 7; ++c) {
            float2 q = *(const float2*)(L + 1 + 2 * c);   // 8B-aligned
#pragma unroll
            for (int h = 0; h < H_N; ++h) h1[h] = fmaf(q.x, wv[1 + 2 * c][h], h1[h]);
#pragma unroll
            for (int h = 0; h < H_N; ++h) h1[h] = fmaf(q.y, wv[2 + 2 * c][h], h1[h]);
        }
        float acc = b3v;
#pragma unroll
        for (int h = 0; h < H_N; ++h) {
            float v = fmaxf(h1[h] + b1v[h], 0.f);
            float u = fmaxf(fmaf(v, w2v[h], b2v[h]), 0.f);
            acc = fmaf(u, w3v[h], acc);
        }
        out[t * TILE_ROWS + wv_id * 64 + lane] = acc;
    };

    // ---- main loop: wave-private, no barriers, counted vmcnt ----
    for (int k = 0; k < TPB; k += 2) {
        // tile k: set A -> buf0
        if (k == 0) asm volatile("s_waitcnt vmcnt(8)" ::: "memory");
        else        asm volatile("s_waitcnt vmcnt(9)" ::: "memory");
        WRITE_SET(a0, a1, a2, a3, a4, a5, a6, a7, 0);
        asm volatile("s_waitcnt lgkmcnt(0)" ::: "memory");
        compute_tile(0, tile0 + k);
        if (k + 2 < TPB) LOAD_SET(a0, a1, a2, a3, a4, a5, a6, a7, tile0 + k + 2);

        // tile k+1: set B -> buf1
        if (k + 1 == TPB - 1) asm volatile("s_waitcnt vmcnt(0)" ::: "memory");
        else                  asm volatile("s_waitcnt vmcnt(9)" ::: "memory");
        WRITE_SET(b0, b1r, b2r, b3r, b4, b5, b6, b7, 1);
        asm volatile("s_waitcnt lgkmcnt(0)" ::: "memory");
        compute_tile(1, tile0 + k + 1);
        if (k + 3 < TPB) LOAD_SET(b0, b1r, b2r, b3r, b4, b5, b6, b7, tile0 + k + 3);
    }
#undef LOAD_SET
#undef WRITE_SET
}

extern "C" void kernel_launch(void* const* d_in, const int* in_sizes, int n_in,
                              void* d_out, int out_size, void* d_ws, size_t ws_size,
                              hipStream_t stream) {
    const float* pa = (const float*)d_in[0];   // (B, D, HIST)
    const float* w1 = (const float*)d_in[1];   // (M, H, D)
    const float* b1 = (const float*)d_in[2];   // (1, H, D)
    const float* b2 = (const float*)d_in[3];   // (1, H, D)
    const float* b3 = (const float*)d_in[4];   // (1, D)
    const float* cw = (const float*)d_in[5];   // (M,)
    const float* ss = (const float*)d_in[6];   // (RANK,)
    const float* sh = (const float*)d_in[7];   // (RANK,)
    const float* al = (const float*)d_in[8];   // (1,)
    const float* rs = (const float*)d_in[9];   // (1,)
    float* out = (float*)d_out;                // (B, D) f32

    fused_kernel<<<NBLOCKS, 256, 0, stream>>>(pa, w1, b1, b2, b3, cw, ss, sh, al, rs, out);
}

// Round 14
// 112.525 us; speedup vs baseline: 2.2527x; 1.0610x over previous
//
#include <hip/hip_runtime.h>
#include <math.h>

#define B_N    32768
#define D_N    128
#define HIST_N 30
#define M_N    15
#define H_N    4

#define TILE_ROWS   256
#define TILE_FLOATS (TILE_ROWS * HIST_N)          // 7680 floats = 30720 B
#define TILE_F4     (TILE_FLOATS / 4)             // 1920 float4
#define WAVE_F4     480                           // per-wave: 64 rows = 480 f4
#define NBLOCKS     256                           // 1 block/CU, one 1.92MB stream per CU
#define TPB         (B_N * D_N / TILE_ROWS / NBLOCKS)   // 64 contiguous tiles

typedef float f32x4 __attribute__((ext_vector_type(4)));

// ---------------------------------------------------------------------------
// Fused persistent kernel, register-staged, wave-private pipeline (r13 body).
// r14 single-variable change: pa loads via __builtin_nontemporal_load (nt
// flag) — the 503MB stream has zero reuse; skip L1/L2/MALL allocation churn.
// Convergence evidence so far: r5(DMA,8w)=121.7, r12(reg,8w)=123.1,
// r13(reg,4w,1-stream)=119.4 -> ~4.4TB/s bus (55% peak) across all configs;
// fills hit 6.8-7.1TB/s. Read-path allocation is the last untested mechanism.
// ---------------------------------------------------------------------------
__global__ __launch_bounds__(256, 2) void fused_kernel(
        const float* __restrict__ pa,
        const float* __restrict__ w1,
        const float* __restrict__ b1,
        const float* __restrict__ b2,
        const float* __restrict__ b3,
        const float* __restrict__ cw,
        const float* __restrict__ ss,
        const float* __restrict__ sh,
        const float* __restrict__ al,
        const float* __restrict__ rs,
        float* __restrict__ out) {
    const int tid   = threadIdx.x;
    const int lane  = tid & 63;
    const int wv_id = tid >> 6;                 // wave 0..3
    const int d     = tid & 127;

    __shared__ __align__(16) f32x4 lds4[2][TILE_F4];      // 2 x 30720 B
    __shared__ float W1c[H_N][D_N];                       // 2 KB
    __shared__ float Gsh[16];
    __shared__ float Msh[32];                             // M2[16], M3[16]

    const f32x4* pa4 = (const f32x4*)pa;
    const size_t tile0 = (size_t)blockIdx.x * TPB;        // contiguous chunk

#define LOAD_SET(v0,v1,v2,v3,v4,v5,v6,v7,t) do {                          \
        const f32x4* s_ = pa4 + (size_t)(t) * TILE_F4 + wv_id * WAVE_F4;  \
        v0 = __builtin_nontemporal_load(s_ + lane);                       \
        v1 = __builtin_nontemporal_load(s_ + 64 + lane);                  \
        v2 = __builtin_nontemporal_load(s_ + 128 + lane);                 \
        v3 = __builtin_nontemporal_load(s_ + 192 + lane);                 \
        v4 = __builtin_nontemporal_load(s_ + 256 + lane);                 \
        v5 = __builtin_nontemporal_load(s_ + 320 + lane);                 \
        v6 = __builtin_nontemporal_load(s_ + 384 + lane);                 \
        if (lane < 32) v7 = __builtin_nontemporal_load(s_ + 448 + lane);  \
    } while (0)

#define WRITE_SET(v0,v1,v2,v3,v4,v5,v6,v7,buf) do {                    \
        f32x4* L_ = &lds4[buf][0] + wv_id * WAVE_F4;                   \
        L_[lane] = v0;        L_[64 + lane] = v1;                      \
        L_[128 + lane] = v2;  L_[192 + lane] = v3;                     \
        L_[256 + lane] = v4;  L_[320 + lane] = v5;                     \
        L_[384 + lane] = v6;                                           \
        if (lane < 32) L_[448 + lane] = v7;                            \
    } while (0)

    f32x4 a0, a1, a2, a3, a4, a5, a6, a7;
    f32x4 b0, b1r, b2r, b3r, b4, b5, b6, b7;
    a7 = (f32x4){0.f, 0.f, 0.f, 0.f};
    b7 = (f32x4){0.f, 0.f, 0.f, 0.f};

    // prologue: tiles 0 and 1 in flight before anything else
    LOAD_SET(a0, a1, a2, a3, a4, a5, a6, a7, tile0);
    LOAD_SET(b0, b1r, b2r, b3r, b4, b5, b6, b7, tile0 + 1);

    // ---- per-d parameter loads (overlap the prologue loads) ----
    float wv[M_N][H_N];
#pragma unroll
    for (int m = 0; m < M_N; ++m)
#pragma unroll
        for (int h = 0; h < H_N; ++h)
            wv[m][h] = w1[(m * H_N + h) * D_N + d];

    float b1v[H_N], b2v[H_N];
#pragma unroll
    for (int h = 0; h < H_N; ++h) {
        b1v[h] = b1[h * D_N + d];
        b2v[h] = b2[h * D_N + d];
    }
    const float b3v = b3[d];

    // ---- softmax(cw), redundant per-thread ----
    float swm[M_N];
    {
        float mx = cw[0];
#pragma unroll
        for (int m = 1; m < M_N; ++m) mx = fmaxf(mx, cw[m]);
        float s = 0.f;
#pragma unroll
        for (int m = 0; m < M_N; ++m) { swm[m] = expf(cw[m] - mx); s += swm[m]; }
        float inv = 1.f / s;
#pragma unroll
        for (int m = 0; m < M_N; ++m) swm[m] *= inv;
    }

    // ---- W1c into LDS ----
    if (tid < 128) {
#pragma unroll
        for (int h = 0; h < H_N; ++h) {
            float acc = 0.f;
#pragma unroll
            for (int m = 0; m < M_N; ++m)
                acc = fmaf(swm[m], w1[(m * H_N + h) * D_N + tid], acc);
            W1c[h][tid] = acc;
        }
    }
    asm volatile("s_waitcnt lgkmcnt(0)" ::: "memory");
    __builtin_amdgcn_s_barrier();

    // ---- Gram (16 threads, staggered) ----
    if (tid < 16) {
        const int i = tid >> 2, j = tid & 3;
        float s = 0.f;
        for (int st = 0; st < 128; ++st) {
            int dd = (st + tid * 8) & 127;
            s = fmaf(W1c[i][dd], W1c[j][dd], s);
        }
        Gsh[tid] = s;
    }
    asm volatile("s_waitcnt lgkmcnt(0)" ::: "memory");
    __builtin_amdgcn_s_barrier();

    // ---- thread 0: Jacobi + two-stage spectral scalars -> M2, M3 ----
    if (tid == 0) {
        float G[4][4], U[4][4];
#pragma unroll
        for (int i = 0; i < 4; ++i)
#pragma unroll
            for (int j = 0; j < 4; ++j) {
                G[i][j] = Gsh[i * 4 + j];
                U[i][j] = (i == j) ? 1.f : 0.f;
            }
        for (int sweep = 0; sweep < 6; ++sweep)
            for (int p = 0; p < 3; ++p)
                for (int q = p + 1; q < 4; ++q) {
                    float apq = G[p][q];
                    if (fabsf(apq) < 1e-30f) continue;
                    float theta = (G[q][q] - G[p][p]) / (2.f * apq);
                    float t = ((theta >= 0.f) ? 1.f : -1.f) /
                              (fabsf(theta) + sqrtf(theta * theta + 1.f));
                    float c = 1.f / sqrtf(t * t + 1.f), sn = t * c;
                    for (int i = 0; i < 4; ++i) {
                        float gip = G[i][p], giq = G[i][q];
                        G[i][p] = c * gip - sn * giq;
                        G[i][q] = sn * gip + c * giq;
                    }
                    for (int i = 0; i < 4; ++i) {
                        float gpi = G[p][i], gqi = G[q][i];
                        G[p][i] = c * gpi - sn * gqi;
                        G[q][i] = sn * gpi + c * gqi;
                    }
                    for (int i = 0; i < 4; ++i) {
                        float uip = U[i][p], uiq = U[i][q];
                        U[i][p] = c * uip - sn * uiq;
                        U[i][q] = sn * uip + c * uiq;
                    }
                }
        float lam[4];
#pragma unroll
        for (int i = 0; i < 4; ++i) lam[i] = G[i][i];
        int ord[4] = {0, 1, 2, 3};
        for (int i = 0; i < 4; ++i)
            for (int j = i + 1; j < 4; ++j)
                if (lam[ord[j]] > lam[ord[i]]) { int t2 = ord[i]; ord[i] = ord[j]; ord[j] = t2; }

        const float a = al[0], r = rs[0];
        float c1[4], S2a[4];
        for (int p = 0; p < 4; ++p) {
            int e = ord[p];
            float S = sqrtf(fmaxf(lam[e], 0.f));
            float x = ss[p];
            float sp = (x > 20.f) ? x : log1pf(expf(x));
            float ratio = (S > 1e-30f) ? ((sp * S + sh[p]) / S) : sp;
            c1[e] = a * ratio + r;
            S2a[e] = fabsf(c1[e]) * S;      // |singular values| of W2
        }
        int ord2[4] = {0, 1, 2, 3};
        for (int i = 0; i < 4; ++i)
            for (int j = i + 1; j < 4; ++j)
                if (S2a[ord2[j]] > S2a[ord2[i]]) { int t2 = ord2[i]; ord2[i] = ord2[j]; ord2[j] = t2; }
        float c12[4];
        for (int p = 0; p < 4; ++p) {
            int e = ord2[p];
            float Sa = S2a[e];
            float x = ss[p];
            float sp = (x > 20.f) ? x : log1pf(expf(x));
            float ratio2 = (Sa > 1e-30f) ? ((sp * Sa + sh[p]) / Sa) : sp;
            c12[e] = (a * ratio2 + r) * c1[e];
        }
#pragma unroll
        for (int i = 0; i < 4; ++i)
#pragma unroll
            for (int j = 0; j < 4; ++j) {
                float m2 = 0.f, m3 = 0.f;
#pragma unroll
                for (int e = 0; e < 4; ++e) {
                    float uu = U[i][e] * U[j][e];
                    m2 = fmaf(uu, c1[e], m2);
                    m3 = fmaf(uu, c12[e], m3);
                }
                Msh[i * 4 + j] = m2;
                Msh[16 + i * 4 + j] = m3;
            }
    }
    asm volatile("s_waitcnt lgkmcnt(0)" ::: "memory");
    __builtin_amdgcn_s_barrier();

    // ---- per-thread W2/W3 columns ----
    float w2v[H_N], w3v[H_N];
#pragma unroll
    for (int h = 0; h < H_N; ++h) {
        float s2 = 0.f, s3 = 0.f;
#pragma unroll
        for (int k4 = 0; k4 < 4; ++k4) {
            float wc = W1c[k4][d];
            s2 = fmaf(Msh[h * 4 + k4], wc, s2);
            s3 = fmaf(Msh[16 + h * 4 + k4], wc, s3);
        }
        w2v[h] = s2;
        w3v[h] = s3;
    }

    // thread computes row = lane of its wave's 64 rows
    const int rd_base = wv_id * (WAVE_F4 * 4) + lane * HIST_N + (HIST_N - M_N);

    auto compute_tile = [&](int buf, size_t t) {
        const float* L = (const float*)&lds4[buf][0] + rd_base;
        float x0 = L[0];
        float h1[H_N];
#pragma unroll
        for (int h = 0; h < H_N; ++h) h1[h] = x0 * wv[0][h];
#pragma unroll
        for (int c = 0; c < 7; ++c) {
            float2 q = *(const float2*)(L + 1 + 2 * c);   // 8B-aligned
#pragma unroll
            for (int h = 0; h < H_N; ++h) h1[h] = fmaf(q.x, wv[1 + 2 * c][h], h1[h]);
#pragma unroll
            for (int h = 0; h < H_N; ++h) h1[h] = fmaf(q.y, wv[2 + 2 * c][h], h1[h]);
        }
        float acc = b3v;
#pragma unroll
        for (int h = 0; h < H_N; ++h) {
            float v = fmaxf(h1[h] + b1v[h], 0.f);
            float u = fmaxf(fmaf(v, w2v[h], b2v[h]), 0.f);
            acc = fmaf(u, w3v[h], acc);
        }
        out[t * TILE_ROWS + wv_id * 64 + lane] = acc;
    };

    // ---- main loop: wave-private, no barriers, counted vmcnt ----
    for (int k = 0; k < TPB; k += 2) {
        // tile k: set A -> buf0
        if (k == 0) asm volatile("s_waitcnt vmcnt(8)" ::: "memory");
        else        asm volatile("s_waitcnt vmcnt(9)" ::: "memory");
        WRITE_SET(a0, a1, a2, a3, a4, a5, a6, a7, 0);
        asm volatile("s_waitcnt lgkmcnt(0)" ::: "memory");
        compute_tile(0, tile0 + k);
        if (k + 2 < TPB) LOAD_SET(a0, a1, a2, a3, a4, a5, a6, a7, tile0 + k + 2);

        // tile k+1: set B -> buf1
        if (k + 1 == TPB - 1) asm volatile("s_waitcnt vmcnt(0)" ::: "memory");
        else                  asm volatile("s_waitcnt vmcnt(9)" ::: "memory");
        WRITE_SET(b0, b1r, b2r, b3r, b4, b5, b6, b7, 1);
        asm volatile("s_waitcnt lgkmcnt(0)" ::: "memory");
        compute_tile(1, tile0 + k + 1);
        if (k + 3 < TPB) LOAD_SET(b0, b1r, b2r, b3r, b4, b5, b6, b7, tile0 + k + 3);
    }
#undef LOAD_SET
#undef WRITE_SET
}

extern "C" void kernel_launch(void* const* d_in, const int* in_sizes, int n_in,
                              void* d_out, int out_size, void* d_ws, size_t ws_size,
                              hipStream_t stream) {
    const float* pa = (const float*)d_in[0];   // (B, D, HIST)
    const float* w1 = (const float*)d_in[1];   // (M, H, D)
    const float* b1 = (const float*)d_in[2];   // (1, H, D)
    const float* b2 = (const float*)d_in[3];   // (1, H, D)
    const float* b3 = (const float*)d_in[4];   // (1, D)
    const float* cw = (const float*)d_in[5];   // (M,)
    const float* ss = (const float*)d_in[6];   // (RANK,)
    const float* sh = (const float*)d_in[7];   // (RANK,)
    const float* al = (const float*)d_in[8];   // (1,)
    const float* rs = (const float*)d_in[9];   // (1,)
    float* out = (float*)d_out;                // (B, D) f32

    fused_kernel<<<NBLOCKS, 256, 0, stream>>>(pa, w1, b1, b2, b3, cw, ss, sh, al, rs, out);
}

// Round 15
// 109.325 us; speedup vs baseline: 2.3187x; 1.0293x over previous
//
#include <hip/hip_runtime.h>
#include <math.h>

#define B_N    32768
#define D_N    128
#define HIST_N 30
#define M_N    15
#define H_N    4

#define TILE_ROWS   512
#define TILE_FLOATS (TILE_ROWS * HIST_N)          // 15360 floats = 61440 B
#define TILE_F4     (TILE_FLOATS / 4)             // 3840 float4
#define WAVE_F4     480                           // per-wave: 64 rows = 480 f4
#define WAVE_FLOATS (WAVE_F4 * 4)                 // 1920 floats
#define NBLOCKS     256                           // 1 block/CU, one stream per CU
#define NTHREADS    512                           // 8 waves/CU (r15 lever: 4 -> 8)
#define TPB         (B_N * D_N / TILE_ROWS / NBLOCKS)   // 32 contiguous tiles

typedef float f32x4 __attribute__((ext_vector_type(4)));

// ---------------------------------------------------------------------------
// Fused persistent kernel, register-staged, wave-private pipeline, NT loads.
// r15 single-variable change vs r14: 512-thread blocks (8 waves/CU, still one
// contiguous per-CU stream; LDS 2x60KB=120KB). Post-NT (112.5us, 4.62TB/s
// effective) the remaining question is whether the read path is TLP-starved
// at 4 waves/CU now that L2/MALL allocation churn is gone.
//   iter k (even->set A/buf0, odd->set B/buf1), per wave:
//     vmcnt(k==0?8 : k==last?0 : 9)   // drain tile k's 8 loads only
//     ds_write set -> buf ; lgkmcnt(0)
//     compute own 64 rows from buf ; store out
//     issue NT loads T_{k+2} into the just-freed set
// ---------------------------------------------------------------------------
__global__ __launch_bounds__(NTHREADS, 1) void fused_kernel(
        const float* __restrict__ pa,
        const float* __restrict__ w1,
        const float* __restrict__ b1,
        const float* __restrict__ b2,
        const float* __restrict__ b3,
        const float* __restrict__ cw,
        const float* __restrict__ ss,
        const float* __restrict__ sh,
        const float* __restrict__ al,
        const float* __restrict__ rs,
        float* __restrict__ out) {
    const int tid   = threadIdx.x;
    const int lane  = tid & 63;
    const int wv_id = tid >> 6;                 // wave 0..7
    const int d     = tid & 127;

    __shared__ __align__(16) f32x4 lds4[2][TILE_F4];      // 2 x 61440 B
    __shared__ float W1c[H_N][D_N];                       // 2 KB
    __shared__ float Gsh[16];
    __shared__ float Msh[32];                             // M2[16], M3[16]

    const f32x4* pa4 = (const f32x4*)pa;
    const size_t tile0 = (size_t)blockIdx.x * TPB;        // contiguous chunk

#define LOAD_SET(v0,v1,v2,v3,v4,v5,v6,v7,t) do {                          \
        const f32x4* s_ = pa4 + (size_t)(t) * TILE_F4 + wv_id * WAVE_F4;  \
        v0 = __builtin_nontemporal_load(s_ + lane);                       \
        v1 = __builtin_nontemporal_load(s_ + 64 + lane);                  \
        v2 = __builtin_nontemporal_load(s_ + 128 + lane);                 \
        v3 = __builtin_nontemporal_load(s_ + 192 + lane);                 \
        v4 = __builtin_nontemporal_load(s_ + 256 + lane);                 \
        v5 = __builtin_nontemporal_load(s_ + 320 + lane);                 \
        v6 = __builtin_nontemporal_load(s_ + 384 + lane);                 \
        if (lane < 32) v7 = __builtin_nontemporal_load(s_ + 448 + lane);  \
    } while (0)

#define WRITE_SET(v0,v1,v2,v3,v4,v5,v6,v7,buf) do {                    \
        f32x4* L_ = &lds4[buf][0] + wv_id * WAVE_F4;                   \
        L_[lane] = v0;        L_[64 + lane] = v1;                      \
        L_[128 + lane] = v2;  L_[192 + lane] = v3;                     \
        L_[256 + lane] = v4;  L_[320 + lane] = v5;                     \
        L_[384 + lane] = v6;                                           \
        if (lane < 32) L_[448 + lane] = v7;                            \
    } while (0)

    f32x4 a0, a1, a2, a3, a4, a5, a6, a7;
    f32x4 b0, b1r, b2r, b3r, b4, b5, b6, b7;
    a7 = (f32x4){0.f, 0.f, 0.f, 0.f};
    b7 = (f32x4){0.f, 0.f, 0.f, 0.f};

    // prologue: tiles 0 and 1 in flight before anything else
    LOAD_SET(a0, a1, a2, a3, a4, a5, a6, a7, tile0);
    LOAD_SET(b0, b1r, b2r, b3r, b4, b5, b6, b7, tile0 + 1);

    // ---- per-d parameter loads (overlap the prologue loads) ----
    float wv[M_N][H_N];
#pragma unroll
    for (int m = 0; m < M_N; ++m)
#pragma unroll
        for (int h = 0; h < H_N; ++h)
            wv[m][h] = w1[(m * H_N + h) * D_N + d];

    float b1v[H_N], b2v[H_N];
#pragma unroll
    for (int h = 0; h < H_N; ++h) {
        b1v[h] = b1[h * D_N + d];
        b2v[h] = b2[h * D_N + d];
    }
    const float b3v = b3[d];

    // ---- softmax(cw), redundant per-thread ----
    float swm[M_N];
    {
        float mx = cw[0];
#pragma unroll
        for (int m = 1; m < M_N; ++m) mx = fmaxf(mx, cw[m]);
        float s = 0.f;
#pragma unroll
        for (int m = 0; m < M_N; ++m) { swm[m] = expf(cw[m] - mx); s += swm[m]; }
        float inv = 1.f / s;
#pragma unroll
        for (int m = 0; m < M_N; ++m) swm[m] *= inv;
    }

    // ---- W1c into LDS ----
    if (tid < 128) {
#pragma unroll
        for (int h = 0; h < H_N; ++h) {
            float acc = 0.f;
#pragma unroll
            for (int m = 0; m < M_N; ++m)
                acc = fmaf(swm[m], w1[(m * H_N + h) * D_N + tid], acc);
            W1c[h][tid] = acc;
        }
    }
    asm volatile("s_waitcnt lgkmcnt(0)" ::: "memory");
    __builtin_amdgcn_s_barrier();

    // ---- Gram (16 threads, staggered) ----
    if (tid < 16) {
        const int i = tid >> 2, j = tid & 3;
        float s = 0.f;
        for (int st = 0; st < 128; ++st) {
            int dd = (st + tid * 8) & 127;
            s = fmaf(W1c[i][dd], W1c[j][dd], s);
        }
        Gsh[tid] = s;
    }
    asm volatile("s_waitcnt lgkmcnt(0)" ::: "memory");
    __builtin_amdgcn_s_barrier();

    // ---- thread 0: Jacobi + two-stage spectral scalars -> M2, M3 ----
    if (tid == 0) {
        float G[4][4], U[4][4];
#pragma unroll
        for (int i = 0; i < 4; ++i)
#pragma unroll
            for (int j = 0; j < 4; ++j) {
                G[i][j] = Gsh[i * 4 + j];
                U[i][j] = (i == j) ? 1.f : 0.f;
            }
        for (int sweep = 0; sweep < 6; ++sweep)
            for (int p = 0; p < 3; ++p)
                for (int q = p + 1; q < 4; ++q) {
                    float apq = G[p][q];
                    if (fabsf(apq) < 1e-30f) continue;
                    float theta = (G[q][q] - G[p][p]) / (2.f * apq);
                    float t = ((theta >= 0.f) ? 1.f : -1.f) /
                              (fabsf(theta) + sqrtf(theta * theta + 1.f));
                    float c = 1.f / sqrtf(t * t + 1.f), sn = t * c;
                    for (int i = 0; i < 4; ++i) {
                        float gip = G[i][p], giq = G[i][q];
                        G[i][p] = c * gip - sn * giq;
                        G[i][q] = sn * gip + c * giq;
                    }
                    for (int i = 0; i < 4; ++i) {
                        float gpi = G[p][i], gqi = G[q][i];
                        G[p][i] = c * gpi - sn * gqi;
                        G[q][i] = sn * gpi + c * gqi;
                    }
                    for (int i = 0; i < 4; ++i) {
                        float uip = U[i][p], uiq = U[i][q];
                        U[i][p] = c * uip - sn * uiq;
                        U[i][q] = sn * uip + c * uiq;
                    }
                }
        float lam[4];
#pragma unroll
        for (int i = 0; i < 4; ++i) lam[i] = G[i][i];
        int ord[4] = {0, 1, 2, 3};
        for (int i = 0; i < 4; ++i)
            for (int j = i + 1; j < 4; ++j)
                if (lam[ord[j]] > lam[ord[i]]) { int t2 = ord[i]; ord[i] = ord[j]; ord[j] = t2; }

        const float a = al[0], r = rs[0];
        float c1[4], S2a[4];
        for (int p = 0; p < 4; ++p) {
            int e = ord[p];
            float S = sqrtf(fmaxf(lam[e], 0.f));
            float x = ss[p];
            float sp = (x > 20.f) ? x : log1pf(expf(x));
            float ratio = (S > 1e-30f) ? ((sp * S + sh[p]) / S) : sp;
            c1[e] = a * ratio + r;
            S2a[e] = fabsf(c1[e]) * S;      // |singular values| of W2
        }
        int ord2[4] = {0, 1, 2, 3};
        for (int i = 0; i < 4; ++i)
            for (int j = i + 1; j < 4; ++j)
                if (S2a[ord2[j]] > S2a[ord2[i]]) { int t2 = ord2[i]; ord2[i] = ord2[j]; ord2[j] = t2; }
        float c12[4];
        for (int p = 0; p < 4; ++p) {
            int e = ord2[p];
            float Sa = S2a[e];
            float x = ss[p];
            float sp = (x > 20.f) ? x : log1pf(expf(x));
            float ratio2 = (Sa > 1e-30f) ? ((sp * Sa + sh[p]) / Sa) : sp;
            c12[e] = (a * ratio2 + r) * c1[e];
        }
#pragma unroll
        for (int i = 0; i < 4; ++i)
#pragma unroll
            for (int j = 0; j < 4; ++j) {
                float m2 = 0.f, m3 = 0.f;
#pragma unroll
                for (int e = 0; e < 4; ++e) {
                    float uu = U[i][e] * U[j][e];
                    m2 = fmaf(uu, c1[e], m2);
                    m3 = fmaf(uu, c12[e], m3);
                }
                Msh[i * 4 + j] = m2;
                Msh[16 + i * 4 + j] = m3;
            }
    }
    asm volatile("s_waitcnt lgkmcnt(0)" ::: "memory");
    __builtin_amdgcn_s_barrier();

    // ---- per-thread W2/W3 columns ----
    float w2v[H_N], w3v[H_N];
#pragma unroll
    for (int h = 0; h < H_N; ++h) {
        float s2 = 0.f, s3 = 0.f;
#pragma unroll
        for (int k4 = 0; k4 < 4; ++k4) {
            float wc = W1c[k4][d];
            s2 = fmaf(Msh[h * 4 + k4], wc, s2);
            s3 = fmaf(Msh[16 + h * 4 + k4], wc, s3);
        }
        w2v[h] = s2;
        w3v[h] = s3;
    }

    // thread computes row = lane of its wave's 64 rows
    const int rd_base = wv_id * WAVE_FLOATS + lane * HIST_N + (HIST_N - M_N);

    auto compute_tile = [&](int buf, size_t t) {
        const float* L = (const float*)&lds4[buf][0] + rd_base;
        float x0 = L[0];
        float h1[H_N];
#pragma unroll
        for (int h = 0; h < H_N; ++h) h1[h] = x0 * wv[0][h];
#pragma unroll
        for (int c = 0; c < 7; ++c) {
            float2 q = *(const float2*)(L + 1 + 2 * c);   // 8B-aligned
#pragma unroll
            for (int h = 0; h < H_N; ++h) h1[h] = fmaf(q.x, wv[1 + 2 * c][h], h1[h]);
#pragma unroll
            for (int h = 0; h < H_N; ++h) h1[h] = fmaf(q.y, wv[2 + 2 * c][h], h1[h]);
        }
        float acc = b3v;
#pragma unroll
        for (int h = 0; h < H_N; ++h) {
            float v = fmaxf(h1[h] + b1v[h], 0.f);
            float u = fmaxf(fmaf(v, w2v[h], b2v[h]), 0.f);
            acc = fmaf(u, w3v[h], acc);
        }
        out[t * TILE_ROWS + wv_id * 64 + lane] = acc;
    };

    // ---- main loop: wave-private, no barriers, counted vmcnt ----
    for (int k = 0; k < TPB; k += 2) {
        // tile k: set A -> buf0
        if (k == 0) asm volatile("s_waitcnt vmcnt(8)" ::: "memory");
        else        asm volatile("s_waitcnt vmcnt(9)" ::: "memory");
        WRITE_SET(a0, a1, a2, a3, a4, a5, a6, a7, 0);
        asm volatile("s_waitcnt lgkmcnt(0)" ::: "memory");
        compute_tile(0, tile0 + k);
        if (k + 2 < TPB) LOAD_SET(a0, a1, a2, a3, a4, a5, a6, a7, tile0 + k + 2);

        // tile k+1: set B -> buf1
        if (k + 1 == TPB - 1) asm volatile("s_waitcnt vmcnt(0)" ::: "memory");
        else                  asm volatile("s_waitcnt vmcnt(9)" ::: "memory");
        WRITE_SET(b0, b1r, b2r, b3r, b4, b5, b6, b7, 1);
        asm volatile("s_waitcnt lgkmcnt(0)" ::: "memory");
        compute_tile(1, tile0 + k + 1);
        if (k + 3 < TPB) LOAD_SET(b0, b1r, b2r, b3r, b4, b5, b6, b7, tile0 + k + 3);
    }
#undef LOAD_SET
#undef WRITE_SET
}

extern "C" void kernel_launch(void* const* d_in, const int* in_sizes, int n_in,
                              void* d_out, int out_size, void* d_ws, size_t ws_size,
                              hipStream_t stream) {
    const float* pa = (const float*)d_in[0];   // (B, D, HIST)
    const float* w1 = (const float*)d_in[1];   // (M, H, D)
    const float* b1 = (const float*)d_in[2];   // (1, H, D)
    const float* b2 = (const float*)d_in[3];   // (1, H, D)
    const float* b3 = (const float*)d_in[4];   // (1, D)
    const float* cw = (const float*)d_in[5];   // (M,)
    const float* ss = (const float*)d_in[6];   // (RANK,)
    const float* sh = (const float*)d_in[7];   // (RANK,)
    const float* al = (const float*)d_in[8];   // (1,)
    const float* rs = (const float*)d_in[9];   // (1,)
    float* out = (float*)d_out;                // (B, D) f32

    fused_kernel<<<NBLOCKS, NTHREADS, 0, stream>>>(pa, w1, b1, b2, b3, cw, ss, sh, al, rs, out);
}